// Round 1
// baseline (746.327 us; speedup 1.0000x reference)
//
#include <hip/hip_runtime.h>
#include <hip/hip_bf16.h>
#include <cstddef>

// Problem constants
#define BB  4
#define SS  2048
#define HH  768
#define NHH 12
#define PHH 64
#define MM  (BB*SS)        // 8192 rows
#define LOG2E 1.4426950408889634f

typedef short  short8  __attribute__((ext_vector_type(8)));
typedef float  floatx4 __attribute__((ext_vector_type(4)));

static __device__ __forceinline__ unsigned short f2bf(float f) {
    unsigned int u = __float_as_uint(f);
    u += 0x7FFF + ((u >> 16) & 1);          // RNE
    return (unsigned short)(u >> 16);
}

// ---------------------------------------------------------------------------
// f32 -> bf16 weight conversion (vectorized: float4 in, 4x bf16 packed out)
// ---------------------------------------------------------------------------
__global__ void mha_convert_w(const float* __restrict__ src,
                              unsigned short* __restrict__ dst, int n4) {
    int i = blockIdx.x * blockDim.x + threadIdx.x;
    if (i < n4) {
        float4 v = reinterpret_cast<const float4*>(src)[i];
        unsigned long long pk =
            (unsigned long long)f2bf(v.x)        |
            ((unsigned long long)f2bf(v.y) << 16) |
            ((unsigned long long)f2bf(v.z) << 32) |
            ((unsigned long long)f2bf(v.w) << 48);
        reinterpret_cast<unsigned long long*>(dst)[i] = pk;
    }
}

// ---------------------------------------------------------------------------
// Per-64x64-tile mask nonzero flags: flags[b][qt][kt], qt,kt in [0,32)
// ---------------------------------------------------------------------------
__global__ void mha_mask_flags(const float* __restrict__ mask,
                               int* __restrict__ flags) {
    int bid = blockIdx.x;                 // 0..4095
    int b   = bid >> 10;
    int rem = bid & 1023;
    int qt  = rem >> 5;
    int kt  = rem & 31;
    const float* base = mask + ((size_t)b*SS + (size_t)qt*64)*SS + kt*64;
    int t    = threadIdx.x;
    int lrow = t >> 4;                    // 0..15
    int lcol = (t & 15) * 4;
    int nz = 0;
    #pragma unroll
    for (int i = 0; i < 4; ++i) {
        float4 v = *reinterpret_cast<const float4*>(base + (size_t)(lrow + 16*i)*SS + lcol);
        nz |= (v.x != 0.f) | (v.y != 0.f) | (v.z != 0.f) | (v.w != 0.f);
    }
    __shared__ int s;
    if (t == 0) s = 0;
    __syncthreads();
    if (nz) s = 1;                         // benign race
    __syncthreads();
    if (t == 0) flags[bid] = s;
}

// ---------------------------------------------------------------------------
// GEMM: Y[M,N] = X[M,K] @ W[N,K]^T + bias   (K = N = 768)
//   MODE 0: write bf16, natural [row*768+col]            (K proj)
//   MODE 1: write bf16 * 0.125, natural                  (Q proj, folds 1/sqrt(64))
//   MODE 2: write bf16 V-transposed: Vt[b][h][d][s]      (V proj)
//   MODE 3: write f32, natural                           (output proj)
// Block = 4 waves; wave w owns rows [bx*64 + w*16, +16), cols [by*64, +64).
// MFMA fragment layouts (v_mfma_f32_16x16x32_bf16):
//   A: lane l holds A[l&15][8*(l>>4)+b], b=0..7 (contiguous 16B)
//   B: lane l holds B[8*(l>>4)+b][l&15]  -> W row (l&15), contiguous 16B
//   D: lane l holds D[(l>>4)*4+r][l&15]
// ---------------------------------------------------------------------------
template<int TIN_F32, int MODE>
__global__ __launch_bounds__(256) void mha_gemm_bt(
        const void* __restrict__ Xv,
        const unsigned short* __restrict__ W,
        const float* __restrict__ bias,
        void* __restrict__ out) {
    const int wave = threadIdx.x >> 6;
    const int lane = threadIdx.x & 63;
    const int lq   = lane & 15;
    const int lg   = lane >> 4;
    const int m0   = blockIdx.x * 64 + wave * 16;
    const int n0   = blockIdx.y * 64;

    floatx4 acc[4];
    #pragma unroll
    for (int n = 0; n < 4; ++n) acc[n] = (floatx4){0.f, 0.f, 0.f, 0.f};

    for (int ko = 0; ko < HH; ko += 32) {
        const int ka = ko + 8*lg;
        short8 a;
        if constexpr (TIN_F32) {
            const float* ap = (const float*)Xv + (size_t)(m0 + lq)*HH + ka;
            float4 v0 = *reinterpret_cast<const float4*>(ap);
            float4 v1 = *reinterpret_cast<const float4*>(ap + 4);
            a[0] = (short)f2bf(v0.x); a[1] = (short)f2bf(v0.y);
            a[2] = (short)f2bf(v0.z); a[3] = (short)f2bf(v0.w);
            a[4] = (short)f2bf(v1.x); a[5] = (short)f2bf(v1.y);
            a[6] = (short)f2bf(v1.z); a[7] = (short)f2bf(v1.w);
        } else {
            a = *reinterpret_cast<const short8*>(
                    (const unsigned short*)Xv + (size_t)(m0 + lq)*HH + ka);
        }
        #pragma unroll
        for (int n = 0; n < 4; ++n) {
            short8 bfr = *reinterpret_cast<const short8*>(
                    W + (size_t)(n0 + n*16 + lq)*HH + ka);
            acc[n] = __builtin_amdgcn_mfma_f32_16x16x32_bf16(a, bfr, acc[n], 0, 0, 0);
        }
    }

    #pragma unroll
    for (int n = 0; n < 4; ++n) {
        const int col = n0 + n*16 + lq;
        const float bv = bias[col];
        #pragma unroll
        for (int r = 0; r < 4; ++r) {
            const int row = m0 + lg*4 + r;
            float y = acc[n][r] + bv;
            if constexpr (MODE == 0) {
                ((unsigned short*)out)[(size_t)row*HH + col] = f2bf(y);
            } else if constexpr (MODE == 1) {
                ((unsigned short*)out)[(size_t)row*HH + col] = f2bf(y * 0.125f);
            } else if constexpr (MODE == 2) {
                int bb = row >> 11, s = row & 2047;
                int hh = col >> 6,  d = col & 63;
                ((unsigned short*)out)[(((size_t)bb*NHH + hh)*PHH + d)*SS + s] = f2bf(y);
            } else {
                ((float*)out)[(size_t)row*HH + col] = y;
            }
        }
    }
}

// ---------------------------------------------------------------------------
// Flash attention: grid = B*NH*(S/64) blocks, 4 waves; wave owns 16 q-rows.
// Q pre-scaled by 0.125. K read [B,S,H] bf16; V read transposed Vt[b][h][d][s].
// Online softmax; P transposed D-layout -> A-layout through padded LDS.
// ---------------------------------------------------------------------------
__global__ __launch_bounds__(256) void mha_flash_attn(
        const unsigned short* __restrict__ qb,
        const unsigned short* __restrict__ kb,
        const unsigned short* __restrict__ vtb,
        const float* __restrict__ mask,
        const int* __restrict__ flags,
        unsigned short* __restrict__ ab) {
    __shared__ short lds_p[4][16][72];     // 72-short row stride breaks conflicts

    const int wave = threadIdx.x >> 6;
    const int lane = threadIdx.x & 63;
    const int lq   = lane & 15;
    const int lg   = lane >> 4;

    int bid = blockIdx.x;                  // b*NH*32 + h*32 + qt
    const int qt = bid & 31;  bid >>= 5;
    const int h  = bid % NHH;
    const int b  = bid / NHH;

    const int q0 = qt*64 + wave*16;        // q row base (within S) for this wave

    // Q A-fragments (held for the whole loop)
    const unsigned short* qp = qb + ((size_t)b*SS + q0 + lq)*HH + h*PHH;
    short8 aq0 = *reinterpret_cast<const short8*>(qp + 8*lg);
    short8 aq1 = *reinterpret_cast<const short8*>(qp + 32 + 8*lg);

    float m_run[4], l_run[4];
    floatx4 oacc[4];
    #pragma unroll
    for (int r = 0; r < 4; ++r) { m_run[r] = -INFINITY; l_run[r] = 0.f; }
    #pragma unroll
    for (int n = 0; n < 4; ++n) oacc[n] = (floatx4){0.f, 0.f, 0.f, 0.f};

    const unsigned short* kbase = kb + (size_t)b*SS*HH + h*PHH;
    const unsigned short* vbase = vtb + ((size_t)b*NHH + h)*(size_t)PHH*SS;
    const float* mbase = mask + (size_t)b*SS*SS + (size_t)(qt*64)*SS;
    const int*   fbase = flags + b*1024 + qt*32;

    for (int kt = 0; kt < 32; ++kt) {
        const int kv0 = kt * 64;

        // --- scores = Q K^T (Q pre-scaled) ---
        floatx4 sacc[4];
        #pragma unroll
        for (int n = 0; n < 4; ++n) sacc[n] = (floatx4){0.f, 0.f, 0.f, 0.f};
        #pragma unroll
        for (int n = 0; n < 4; ++n) {
            const unsigned short* kr = kbase + (size_t)(kv0 + n*16 + lq)*HH;
            short8 bk0 = *reinterpret_cast<const short8*>(kr + 8*lg);
            short8 bk1 = *reinterpret_cast<const short8*>(kr + 32 + 8*lg);
            sacc[n] = __builtin_amdgcn_mfma_f32_16x16x32_bf16(aq0, bk0, sacc[n], 0, 0, 0);
            sacc[n] = __builtin_amdgcn_mfma_f32_16x16x32_bf16(aq1, bk1, sacc[n], 0, 0, 0);
        }

        // --- additive mask (skipped when the 64x64 tile is all zero) ---
        if (fbase[kt]) {
            #pragma unroll
            for (int n = 0; n < 4; ++n)
                #pragma unroll
                for (int r = 0; r < 4; ++r)
                    sacc[n][r] += mbase[(size_t)(wave*16 + lg*4 + r)*SS + kv0 + n*16 + lq];
        }

        // --- online softmax (rows live across the 16 lanes of a lane-group) ---
        float tmax[4];
        #pragma unroll
        for (int r = 0; r < 4; ++r) {
            tmax[r] = fmaxf(fmaxf(sacc[0][r], sacc[1][r]), fmaxf(sacc[2][r], sacc[3][r]));
        }
        #pragma unroll
        for (int off = 1; off < 16; off <<= 1)
            #pragma unroll
            for (int r = 0; r < 4; ++r)
                tmax[r] = fmaxf(tmax[r], __shfl_xor(tmax[r], off));

        float corr[4], psum[4];
        #pragma unroll
        for (int r = 0; r < 4; ++r) {
            float mnew = fmaxf(m_run[r], tmax[r]);
            corr[r] = exp2f((m_run[r] - mnew) * LOG2E);
            m_run[r] = mnew;
            psum[r] = 0.f;
        }
        #pragma unroll
        for (int n = 0; n < 4; ++n) {
            #pragma unroll
            for (int r = 0; r < 4; ++r) {
                float p = exp2f((sacc[n][r] - m_run[r]) * LOG2E);
                psum[r] += p;
                lds_p[wave][lg*4 + r][n*16 + lq] = (short)f2bf(p);
            }
        }
        #pragma unroll
        for (int off = 1; off < 16; off <<= 1)
            #pragma unroll
            for (int r = 0; r < 4; ++r)
                psum[r] += __shfl_xor(psum[r], off);
        #pragma unroll
        for (int r = 0; r < 4; ++r) l_run[r] = l_run[r]*corr[r] + psum[r];
        #pragma unroll
        for (int n = 0; n < 4; ++n)
            #pragma unroll
            for (int r = 0; r < 4; ++r)
                oacc[n][r] *= corr[r];

        __syncthreads();   // P writes visible before A-layout reads

        short8 pa0 = *reinterpret_cast<const short8*>(&lds_p[wave][lq][8*lg]);
        short8 pa1 = *reinterpret_cast<const short8*>(&lds_p[wave][lq][32 + 8*lg]);

        // --- O += P V  (B-operand from transposed V: contiguous along s) ---
        #pragma unroll
        for (int n = 0; n < 4; ++n) {
            const unsigned short* vr = vbase + (size_t)(n*16 + lq)*SS + kv0;
            short8 bv0 = *reinterpret_cast<const short8*>(vr + 8*lg);
            short8 bv1 = *reinterpret_cast<const short8*>(vr + 32 + 8*lg);
            oacc[n] = __builtin_amdgcn_mfma_f32_16x16x32_bf16(pa0, bv0, oacc[n], 0, 0, 0);
            oacc[n] = __builtin_amdgcn_mfma_f32_16x16x32_bf16(pa1, bv1, oacc[n], 0, 0, 0);
        }

        __syncthreads();   // reads done before next iteration overwrites lds_p
    }

    float inv[4];
    #pragma unroll
    for (int r = 0; r < 4; ++r) inv[r] = 1.f / l_run[r];
    #pragma unroll
    for (int n = 0; n < 4; ++n)
        #pragma unroll
        for (int r = 0; r < 4; ++r)
            ab[((size_t)b*SS + q0 + lg*4 + r)*HH + h*PHH + n*16 + lq] =
                f2bf(oacc[n][r] * inv[r]);
}

// ---------------------------------------------------------------------------
extern "C" void kernel_launch(void* const* d_in, const int* in_sizes, int n_in,
                              void* d_out, int out_size, void* d_ws, size_t ws_size,
                              hipStream_t stream) {
    const float* key   = (const float*)d_in[0];
    const float* value = (const float*)d_in[1];
    const float* query = (const float*)d_in[2];
    const float* mask  = (const float*)d_in[3];
    const float* Wq    = (const float*)d_in[4];
    const float* bq    = (const float*)d_in[5];
    const float* Wk    = (const float*)d_in[6];
    const float* bk    = (const float*)d_in[7];
    const float* Wv    = (const float*)d_in[8];
    const float* bv    = (const float*)d_in[9];
    const float* Wo    = (const float*)d_in[10];
    const float* bo    = (const float*)d_in[11];
    float* out = (float*)d_out;

    const size_t WSZ = (size_t)HH * HH;       // 589824
    const size_t ASZ = (size_t)MM * HH;       // 6291456
    unsigned short* wqb = (unsigned short*)d_ws;
    unsigned short* wkb = wqb + WSZ;
    unsigned short* wvb = wkb + WSZ;
    unsigned short* wob = wvb + WSZ;
    unsigned short* qb  = wob + WSZ;
    unsigned short* kb  = qb + ASZ;
    unsigned short* vtb = kb + ASZ;
    unsigned short* ab  = vtb + ASZ;
    int* flags = (int*)(ab + ASZ);            // 4096 ints

    // weights -> bf16
    const int n4 = (int)(WSZ / 4);            // 147456
    mha_convert_w<<<(n4 + 255)/256, 256, 0, stream>>>(Wq, wqb, n4);
    mha_convert_w<<<(n4 + 255)/256, 256, 0, stream>>>(Wk, wkb, n4);
    mha_convert_w<<<(n4 + 255)/256, 256, 0, stream>>>(Wv, wvb, n4);
    mha_convert_w<<<(n4 + 255)/256, 256, 0, stream>>>(Wo, wob, n4);

    // mask tile flags
    mha_mask_flags<<<BB*32*32, 256, 0, stream>>>(mask, flags);

    // projections
    dim3 g(MM/64, HH/64);
    mha_gemm_bt<1,1><<<g, 256, 0, stream>>>(query, wqb, bq, qb);   // Q (scaled)
    mha_gemm_bt<1,0><<<g, 256, 0, stream>>>(key,   wkb, bk, kb);   // K
    mha_gemm_bt<1,2><<<g, 256, 0, stream>>>(value, wvb, bv, vtb);  // V (transposed)

    // attention
    mha_flash_attn<<<BB*NHH*(SS/64), 256, 0, stream>>>(qb, kb, vtb, mask, flags, ab);

    // output projection -> f32
    mha_gemm_bt<0,3><<<g, 256, 0, stream>>>(ab, wob, bo, out);
}

// Round 2
// 307.606 us; speedup vs baseline: 2.4262x; 2.4262x over previous
//
#include <hip/hip_runtime.h>
#include <hip/hip_bf16.h>
#include <cstddef>
#include <cstdint>

#define BB  4
#define SS  2048
#define HH  768
#define NHH 12
#define PHH 64
#define MM  (BB*SS)        // 8192 rows
#define LOG2E 1.4426950408889634f

typedef short         short8   __attribute__((ext_vector_type(8)));
typedef float         floatx4  __attribute__((ext_vector_type(4)));
typedef float         floatx16 __attribute__((ext_vector_type(16)));
typedef unsigned int  uint4v   __attribute__((ext_vector_type(4)));

static __device__ __forceinline__ unsigned short f2bf(float f) {
    unsigned int u = __float_as_uint(f);
    u += 0x7FFF + ((u >> 16) & 1);          // RNE
    return (unsigned short)(u >> 16);
}

static __device__ __forceinline__ unsigned int cvtpk_bf16(float lo, float hi) {
    unsigned int r;
    asm("v_cvt_pk_bf16_f32 %0, %1, %2" : "=v"(r) : "v"(lo), "v"(hi));
    return r;
}

static __device__ __forceinline__ short8 mk_short8(unsigned int a, unsigned int b,
                                                   unsigned int c, unsigned int d) {
    uint4v u = {a, b, c, d};
    return __builtin_bit_cast(short8, u);
}

#define GLOAD_LDS16(g, l) __builtin_amdgcn_global_load_lds(            \
        (const __attribute__((address_space(1))) void*)(g),            \
        (__attribute__((address_space(3))) void*)(l), 16, 0, 0)

// ---------------------------------------------------------------------------
// f32 -> bf16 conversion (float4 in, 4x bf16 packed out)
// ---------------------------------------------------------------------------
__global__ void mha_cvt_bf16(const float* __restrict__ src,
                             unsigned short* __restrict__ dst, int n4) {
    int i = blockIdx.x * blockDim.x + threadIdx.x;
    if (i < n4) {
        float4 v = reinterpret_cast<const float4*>(src)[i];
        unsigned long long pk =
            (unsigned long long)f2bf(v.x)         |
            ((unsigned long long)f2bf(v.y) << 16) |
            ((unsigned long long)f2bf(v.z) << 32) |
            ((unsigned long long)f2bf(v.w) << 48);
        reinterpret_cast<unsigned long long*>(dst)[i] = pk;
    }
}

// ---------------------------------------------------------------------------
// Per-64x64-tile mask nonzero flags: flags[b][qt][kt], qt,kt in [0,32)
// ---------------------------------------------------------------------------
__global__ void mha_mask_flags(const float* __restrict__ mask,
                               int* __restrict__ flags) {
    int bid = blockIdx.x;                 // 0..4095
    int b   = bid >> 10;
    int rem = bid & 1023;
    int qt  = rem >> 5;
    int kt  = rem & 31;
    const float* base = mask + ((size_t)b*SS + (size_t)qt*64)*SS + kt*64;
    int t    = threadIdx.x;
    int lrow = t >> 4;                    // 0..15
    int lcol = (t & 15) * 4;
    int nz = 0;
    #pragma unroll
    for (int i = 0; i < 4; ++i) {
        float4 v = *reinterpret_cast<const float4*>(base + (size_t)(lrow + 16*i)*SS + lcol);
        nz |= (v.x != 0.f) | (v.y != 0.f) | (v.z != 0.f) | (v.w != 0.f);
    }
    __shared__ int s;
    if (t == 0) s = 0;
    __syncthreads();
    if (nz) s = 1;                         // benign race
    __syncthreads();
    if (t == 0) flags[bid] = s;
}

// ---------------------------------------------------------------------------
// GEMM: Y[M,N] = X[M,768] @ W[768,768]^T + bias, bf16 inputs, m97-style.
// Tile 64(M) x 128(N), BK=32, 4 waves; wave w owns cols [32w,32w+32).
// LDS staged via global_load_lds width=16 (linear layout, wave-uniform base).
//   MODE 0: bf16 natural     MODE 1: bf16*0.125 (Q)
//   MODE 2: bf16 Vt[b][h][d][s]   MODE 3: f32 natural
// ---------------------------------------------------------------------------
template<int MODE>
__global__ __launch_bounds__(256) void mha_gemm(
        const unsigned short* __restrict__ X,
        const unsigned short* __restrict__ W,
        const float* __restrict__ bias,
        void* __restrict__ out) {
    __shared__ unsigned short As[64 * 32];      // [64][32]
    __shared__ unsigned short Bs[128 * 32];     // [128][32]
    const int wave = threadIdx.x >> 6;
    const int lane = threadIdx.x & 63;
    const int lq = lane & 15, lg = lane >> 4;
    const int m0 = blockIdx.x * 64;
    const int n0 = blockIdx.y * 128;
    const int srow = lane >> 2;                 // 0..15
    const int scol = 8 * (lane & 3);            // 0,8,16,24

    const unsigned short* Xr  = X + (size_t)(m0 + wave*16 + srow)*HH + scol;
    const unsigned short* Wr0 = W + (size_t)(n0 + wave*32 + srow)*HH + scol;
    const unsigned short* Wr1 = W + (size_t)(n0 + wave*32 + 16 + srow)*HH + scol;
    unsigned short* As_d  = As + wave*512;      // 16 rows * 32 cols
    unsigned short* Bs_d0 = Bs + wave*1024;
    unsigned short* Bs_d1 = Bs + wave*1024 + 512;

    floatx4 acc[4][2];
    #pragma unroll
    for (int m = 0; m < 4; ++m)
        #pragma unroll
        for (int n = 0; n < 2; ++n) acc[m][n] = (floatx4){0.f, 0.f, 0.f, 0.f};

    for (int k0 = 0; k0 < HH; k0 += 32) {
        GLOAD_LDS16(Xr  + k0, As_d);
        GLOAD_LDS16(Wr0 + k0, Bs_d0);
        GLOAD_LDS16(Wr1 + k0, Bs_d1);
        __syncthreads();
        short8 af[4], bw[2];
        #pragma unroll
        for (int m = 0; m < 4; ++m)
            af[m] = *reinterpret_cast<const short8*>(As + (16*m + lq)*32 + 8*lg);
        #pragma unroll
        for (int n = 0; n < 2; ++n)
            bw[n] = *reinterpret_cast<const short8*>(Bs + (32*wave + 16*n + lq)*32 + 8*lg);
        #pragma unroll
        for (int m = 0; m < 4; ++m)
            #pragma unroll
            for (int n = 0; n < 2; ++n)
                acc[m][n] = __builtin_amdgcn_mfma_f32_16x16x32_bf16(af[m], bw[n], acc[m][n], 0, 0, 0);
        __syncthreads();
    }

    #pragma unroll
    for (int n = 0; n < 2; ++n) {
        const int col = n0 + wave*32 + 16*n + lq;
        const float bv = bias[col];
        #pragma unroll
        for (int m = 0; m < 4; ++m) {
            #pragma unroll
            for (int r = 0; r < 4; ++r) {
                const int row = m0 + 16*m + 4*lg + r;
                float y = acc[m][n][r] + bv;
                if constexpr (MODE == 0) {
                    ((unsigned short*)out)[(size_t)row*HH + col] = f2bf(y);
                } else if constexpr (MODE == 1) {
                    ((unsigned short*)out)[(size_t)row*HH + col] = f2bf(y * 0.125f);
                } else if constexpr (MODE == 2) {
                    int bb = row >> 11, s = row & 2047;
                    int hh = col >> 6,  d = col & 63;
                    ((unsigned short*)out)[(((size_t)bb*NHH + hh)*PHH + d)*SS + s] = f2bf(y);
                } else {
                    ((float*)out)[(size_t)row*HH + col] = y;
                }
            }
        }
    }
}

// ---------------------------------------------------------------------------
// Attention, swapped-operand 32x32x16 MFMA. Grid = B*NH*(S/128), 4 waves.
// Wave owns 32 q-rows. Lane (col=l&31) owns one q-row: softmax fully
// in-register (one shfl_xor(32) per reduce). No LDS, no barriers.
//   S^T = mfma(K_frag, Q_frag):  D[kv][q], kv = (r&3)+8*(r>>2)+4*hi
//   O^T = mfma(Vt_frag, P_frag): D[d][q],  d  = (r&3)+8*(r>>2)+4*hi
// ---------------------------------------------------------------------------
__global__ __launch_bounds__(256) void mha_attn(
        const unsigned short* __restrict__ qb,
        const unsigned short* __restrict__ kb,
        const unsigned short* __restrict__ vtb,
        const float* __restrict__ mask,
        const int* __restrict__ flags,
        unsigned short* __restrict__ ab) {
    const int wave = threadIdx.x >> 6;
    const int lane = threadIdx.x & 63;
    const int ql   = lane & 31;            // q-local == D column
    const int hi   = lane >> 5;

    int bid = blockIdx.x;
    bid = (bid & 7) * 96 + (bid >> 3);     // XCD swizzle (768 = 8*96, bijective)
    const int qblk = bid & 15;
    int t = bid >> 4;
    const int h = t % NHH;
    const int b = t / NHH;

    const int q0 = qblk*128 + wave*32;
    const int q  = q0 + ql;

    // Q B-fragments (lane's own q-row), held all loop
    const unsigned short* qp = qb + ((size_t)b*SS + q)*HH + h*PHH + 8*hi;
    short8 qf[4];
    #pragma unroll
    for (int ks = 0; ks < 4; ++ks)
        qf[ks] = *reinterpret_cast<const short8*>(qp + 16*ks);

    const unsigned short* kp = kb + (size_t)b*SS*HH + h*PHH + 8*hi;
    const unsigned short* vp = vtb + ((size_t)b*NHH + h)*(size_t)PHH*SS;
    const int* fbase = flags + b*1024 + (q0 >> 6)*32;

    float m_run = -INFINITY, l_run = 0.f;
    floatx16 o0, o1;
    #pragma unroll
    for (int i = 0; i < 16; ++i) { o0[i] = 0.f; o1[i] = 0.f; }

    for (int kt = 0; kt < 32; ++kt) {
        const int kv0 = kt * 64;

        // ---- K fragments + QK^T (swapped) ----
        const unsigned short* kr0 = kp + (size_t)(kv0 + ql)*HH;
        const unsigned short* kr1 = kp + (size_t)(kv0 + 32 + ql)*HH;
        short8 kf0[4], kf1[4];
        #pragma unroll
        for (int ks = 0; ks < 4; ++ks) {
            kf0[ks] = *reinterpret_cast<const short8*>(kr0 + 16*ks);
            kf1[ks] = *reinterpret_cast<const short8*>(kr1 + 16*ks);
        }
        floatx16 s0, s1;
        #pragma unroll
        for (int i = 0; i < 16; ++i) { s0[i] = 0.f; s1[i] = 0.f; }
        __builtin_amdgcn_s_setprio(1);
        #pragma unroll
        for (int ks = 0; ks < 4; ++ks) {
            s0 = __builtin_amdgcn_mfma_f32_32x32x16_bf16(kf0[ks], qf[ks], s0, 0, 0, 0);
            s1 = __builtin_amdgcn_mfma_f32_32x32x16_bf16(kf1[ks], qf[ks], s1, 0, 0, 0);
        }
        __builtin_amdgcn_s_setprio(0);

        // ---- issue V loads early (hide under softmax) ----
        const unsigned short* vr0 = vp + (size_t)ql*SS + kv0 + 8*hi;
        const unsigned short* vr1 = vp + (size_t)(32 + ql)*SS + kv0 + 8*hi;
        short8 vf0[4], vf1[4];
        #pragma unroll
        for (int ks = 0; ks < 4; ++ks) {
            vf0[ks] = *reinterpret_cast<const short8*>(vr0 + 16*ks);
            vf1[ks] = *reinterpret_cast<const short8*>(vr1 + 16*ks);
        }

        // ---- additive mask (cold path; flags tile-sparse) ----
        if (fbase[kt]) {
            const float* mrow = mask + ((size_t)b*SS + q)*SS + kv0;
            #pragma unroll
            for (int g = 0; g < 4; ++g) {
                float4 a = *reinterpret_cast<const float4*>(mrow + 8*g + 4*hi);
                float4 c = *reinterpret_cast<const float4*>(mrow + 32 + 8*g + 4*hi);
                s0[4*g+0] += a.x; s0[4*g+1] += a.y; s0[4*g+2] += a.z; s0[4*g+3] += a.w;
                s1[4*g+0] += c.x; s1[4*g+1] += c.y; s1[4*g+2] += c.z; s1[4*g+3] += c.w;
            }
        }

        // ---- online softmax, per-lane (lane owns row q) ----
        float t0 = s0[0], t1 = s0[1], t2 = s0[2], t3 = s0[3];
        #pragma unroll
        for (int r = 4; r < 16; r += 4) {
            t0 = fmaxf(t0, s0[r+0]); t1 = fmaxf(t1, s0[r+1]);
            t2 = fmaxf(t2, s0[r+2]); t3 = fmaxf(t3, s0[r+3]);
        }
        #pragma unroll
        for (int r = 0; r < 16; r += 4) {
            t0 = fmaxf(t0, s1[r+0]); t1 = fmaxf(t1, s1[r+1]);
            t2 = fmaxf(t2, s1[r+2]); t3 = fmaxf(t3, s1[r+3]);
        }
        float pm = fmaxf(fmaxf(t0, t1), fmaxf(t2, t3));
        pm = fmaxf(pm, __shfl_xor(pm, 32));

        if (!__all(pm - m_run <= 8.f)) {       // defer-max (T13)
            float mnew = fmaxf(m_run, pm);
            float corr = exp2f((m_run - mnew) * LOG2E);
            m_run = mnew;
            l_run *= corr;
            #pragma unroll
            for (int i = 0; i < 16; ++i) { o0[i] *= corr; o1[i] *= corr; }
        }
        const float msc = m_run * LOG2E;
        float ps0 = 0.f, ps1 = 0.f, ps2 = 0.f, ps3 = 0.f;
        #pragma unroll
        for (int r = 0; r < 16; r += 4) {
            s0[r+0] = exp2f(fmaf(s0[r+0], LOG2E, -msc)); ps0 += s0[r+0];
            s0[r+1] = exp2f(fmaf(s0[r+1], LOG2E, -msc)); ps1 += s0[r+1];
            s0[r+2] = exp2f(fmaf(s0[r+2], LOG2E, -msc)); ps2 += s0[r+2];
            s0[r+3] = exp2f(fmaf(s0[r+3], LOG2E, -msc)); ps3 += s0[r+3];
        }
        #pragma unroll
        for (int r = 0; r < 16; r += 4) {
            s1[r+0] = exp2f(fmaf(s1[r+0], LOG2E, -msc)); ps0 += s1[r+0];
            s1[r+1] = exp2f(fmaf(s1[r+1], LOG2E, -msc)); ps1 += s1[r+1];
            s1[r+2] = exp2f(fmaf(s1[r+2], LOG2E, -msc)); ps2 += s1[r+2];
            s1[r+3] = exp2f(fmaf(s1[r+3], LOG2E, -msc)); ps3 += s1[r+3];
        }
        float ps = (ps0 + ps1) + (ps2 + ps3);
        ps += __shfl_xor(ps, 32);
        l_run += ps;

        // ---- P -> bf16 A/B-fragments via cvt_pk + half-swap ----
        unsigned int c0 = cvtpk_bf16(s0[0],  s0[1]),  c1 = cvtpk_bf16(s0[2],  s0[3]);
        unsigned int c2 = cvtpk_bf16(s0[4],  s0[5]),  c3 = cvtpk_bf16(s0[6],  s0[7]);
        unsigned int c4 = cvtpk_bf16(s0[8],  s0[9]),  c5 = cvtpk_bf16(s0[10], s0[11]);
        unsigned int c6 = cvtpk_bf16(s0[12], s0[13]), c7 = cvtpk_bf16(s0[14], s0[15]);
        unsigned int d0 = cvtpk_bf16(s1[0],  s1[1]),  d1 = cvtpk_bf16(s1[2],  s1[3]);
        unsigned int d2 = cvtpk_bf16(s1[4],  s1[5]),  d3 = cvtpk_bf16(s1[6],  s1[7]);
        unsigned int d4 = cvtpk_bf16(s1[8],  s1[9]),  d5 = cvtpk_bf16(s1[10], s1[11]);
        unsigned int d6 = cvtpk_bf16(s1[12], s1[13]), d7 = cvtpk_bf16(s1[14], s1[15]);

        short8 pa[4];
        {
            unsigned int x0 = __shfl_xor(c0, 32), x1 = __shfl_xor(c1, 32);
            unsigned int x2 = __shfl_xor(c2, 32), x3 = __shfl_xor(c3, 32);
            pa[0] = mk_short8(hi ? x2 : c0, hi ? x3 : c1, hi ? c2 : x0, hi ? c3 : x1);
            unsigned int y4 = __shfl_xor(c4, 32), y5 = __shfl_xor(c5, 32);
            unsigned int y6 = __shfl_xor(c6, 32), y7 = __shfl_xor(c7, 32);
            pa[1] = mk_short8(hi ? y6 : c4, hi ? y7 : c5, hi ? c6 : y4, hi ? c7 : y5);
            unsigned int z0 = __shfl_xor(d0, 32), z1 = __shfl_xor(d1, 32);
            unsigned int z2 = __shfl_xor(d2, 32), z3 = __shfl_xor(d3, 32);
            pa[2] = mk_short8(hi ? z2 : d0, hi ? z3 : d1, hi ? d2 : z0, hi ? d3 : z1);
            unsigned int w4 = __shfl_xor(d4, 32), w5 = __shfl_xor(d5, 32);
            unsigned int w6 = __shfl_xor(d6, 32), w7 = __shfl_xor(d7, 32);
            pa[3] = mk_short8(hi ? w6 : d4, hi ? w7 : d5, hi ? d6 : w4, hi ? d7 : w5);
        }

        // ---- O^T += V^T P^T (swapped PV) ----
        __builtin_amdgcn_s_setprio(1);
        #pragma unroll
        for (int ks = 0; ks < 4; ++ks) {
            o0 = __builtin_amdgcn_mfma_f32_32x32x16_bf16(vf0[ks], pa[ks], o0, 0, 0, 0);
            o1 = __builtin_amdgcn_mfma_f32_32x32x16_bf16(vf1[ks], pa[ks], o1, 0, 0, 0);
        }
        __builtin_amdgcn_s_setprio(0);
    }

    // ---- epilogue: O[q][d], d = (r&3)+8*(r>>2)+4*hi (+32 for o1) ----
    const float inv = 1.f / l_run;
    unsigned short* op = ab + ((size_t)b*SS + q)*HH + h*PHH + 4*hi;
    #pragma unroll
    for (int g = 0; g < 4; ++g) {
        ushort4 w0, w1;
        w0.x = f2bf(o0[4*g+0]*inv); w0.y = f2bf(o0[4*g+1]*inv);
        w0.z = f2bf(o0[4*g+2]*inv); w0.w = f2bf(o0[4*g+3]*inv);
        w1.x = f2bf(o1[4*g+0]*inv); w1.y = f2bf(o1[4*g+1]*inv);
        w1.z = f2bf(o1[4*g+2]*inv); w1.w = f2bf(o1[4*g+3]*inv);
        *reinterpret_cast<ushort4*>(op + 8*g)      = w0;
        *reinterpret_cast<ushort4*>(op + 32 + 8*g) = w1;
    }
}

// ---------------------------------------------------------------------------
extern "C" void kernel_launch(void* const* d_in, const int* in_sizes, int n_in,
                              void* d_out, int out_size, void* d_ws, size_t ws_size,
                              hipStream_t stream) {
    const float* key   = (const float*)d_in[0];
    const float* value = (const float*)d_in[1];
    const float* query = (const float*)d_in[2];
    const float* mask  = (const float*)d_in[3];
    const float* Wq    = (const float*)d_in[4];
    const float* bq    = (const float*)d_in[5];
    const float* Wk    = (const float*)d_in[6];
    const float* bk    = (const float*)d_in[7];
    const float* Wv    = (const float*)d_in[8];
    const float* bv    = (const float*)d_in[9];
    const float* Wo    = (const float*)d_in[10];
    const float* bo    = (const float*)d_in[11];
    float* out = (float*)d_out;

    const size_t WSZ = (size_t)HH * HH;       // 589824
    const size_t ASZ = (size_t)MM * HH;       // 6291456
    unsigned short* wqb = (unsigned short*)d_ws;
    unsigned short* wkb = wqb + WSZ;
    unsigned short* wvb = wkb + WSZ;
    unsigned short* wob = wvb + WSZ;
    unsigned short* qb  = wob + WSZ;
    unsigned short* kb  = qb + ASZ;
    unsigned short* vtb = kb + ASZ;
    unsigned short* xb  = vtb + ASZ;          // convert scratch, later attn out
    int* flags = (int*)(xb + ASZ);            // 4096 ints

    // weights -> bf16
    const int wn4 = (int)(WSZ / 4);
    mha_cvt_bf16<<<(wn4 + 255)/256, 256, 0, stream>>>(Wq, wqb, wn4);
    mha_cvt_bf16<<<(wn4 + 255)/256, 256, 0, stream>>>(Wk, wkb, wn4);
    mha_cvt_bf16<<<(wn4 + 255)/256, 256, 0, stream>>>(Wv, wvb, wn4);
    mha_cvt_bf16<<<(wn4 + 255)/256, 256, 0, stream>>>(Wo, wob, wn4);

    // mask tile flags
    mha_mask_flags<<<BB*32*32, 256, 0, stream>>>(mask, flags);

    // projections (activation converted once per input, buffer reused)
    const int an4 = (int)(ASZ / 4);
    dim3 g(MM/64, HH/128);
    mha_cvt_bf16<<<(an4 + 255)/256, 256, 0, stream>>>(query, xb, an4);
    mha_gemm<1><<<g, 256, 0, stream>>>(xb, wqb, bq, qb);    // Q (pre-scaled)
    mha_cvt_bf16<<<(an4 + 255)/256, 256, 0, stream>>>(key, xb, an4);
    mha_gemm<0><<<g, 256, 0, stream>>>(xb, wkb, bk, kb);    // K
    mha_cvt_bf16<<<(an4 + 255)/256, 256, 0, stream>>>(value, xb, an4);
    mha_gemm<2><<<g, 256, 0, stream>>>(xb, wvb, bv, vtb);   // V (transposed)

    // attention (writes xb as bf16 [B,S,H])
    mha_attn<<<BB*NHH*(SS/128), 256, 0, stream>>>(qb, kb, vtb, mask, flags, xb);

    // output projection -> f32
    mha_gemm<3><<<g, 256, 0, stream>>>(xb, wob, bo, out);
}